// Round 8
// baseline (207.498 us; speedup 1.0000x reference)
//
#include <hip/hip_runtime.h>
#include <cmath>

typedef _Float16 f16;
typedef _Float16 f16x8 __attribute__((ext_vector_type(8)));
typedef _Float16 f16x4 __attribute__((ext_vector_type(4)));
typedef float    f32x4 __attribute__((ext_vector_type(4)));
typedef unsigned int u32;
typedef u32 u32x4 __attribute__((ext_vector_type(4)));

#define C_   192
#define HH   56
#define WW   56
#define NN   3136
#define BB   8
#define MM   784
#define NHEAD 4
#define HD   48
#define VT_LD 800            // padded key-dim of transposed V (784 + 16)
#define QPB  (BB*NN/64)      // 392 proj blocks, Q path
#define KVPB (BB*MM/64)      // 98 proj blocks, KV path

#define MFMA16(a,b,c) __builtin_amdgcn_mfma_f32_16x16x32_f16(a,b,c,0,0,0)

static __device__ __forceinline__ u32 pkrtz(float a, float b) {
    typedef __fp16 fp16x2 __attribute__((ext_vector_type(2)));
    fp16x2 h = __builtin_amdgcn_cvt_pkrtz(a, b);
    return __builtin_bit_cast(u32, h);
}

// ---------------------------------------------------------------------------
// Setup: blocks 0..575 = fold pointwise into projections (3 x 192 rows),
// blocks 576..703 = zero Vt pad columns m=784..799.  block = 192 threads.
__global__ __launch_bounds__(192) void setup_kernel(
    const float* __restrict__ Wq, const float* __restrict__ Wk,
    const float* __restrict__ Wv, const float* __restrict__ pw_q,
    const float* __restrict__ pw_kv,
    f16* __restrict__ Mq, f16* __restrict__ Mk, f16* __restrict__ Mv,
    f16* __restrict__ vt)
{
    int blk = blockIdx.x, tid = threadIdx.x;
    if (blk < 576) {
        int which = blk / 192, o = blk % 192;
        const float* Wm = which == 0 ? Wq : (which == 1 ? Wk : Wv);
        const float* P  = which == 0 ? pw_q : (which == 1 ? pw_kv : pw_kv + C_*C_);
        f16* Mo         = which == 0 ? Mq : (which == 1 ? Mk : Mv);
        __shared__ float wrow[C_];
        wrow[tid] = Wm[o*C_ + tid];
        __syncthreads();
        float acc = 0.f;
        #pragma unroll 8
        for (int j = 0; j < C_; ++j)
            acc = fmaf(wrow[j], P[j*C_ + tid], acc);
        Mo[o*C_ + tid] = (f16)acc;
    } else {
        int i = (blk - 576)*192 + tid;          // 24576 pad elements exactly
        int b = i / (C_*16);
        int rem = i % (C_*16);
        int c = rem / 16;
        int m = MM + (rem & 15);
        vt[((size_t)b*C_ + c)*VT_LD + m] = (f16)0.f;
    }
}

// ---------------------------------------------------------------------------
// Depthwise 3x3 + BN for both paths in one launch. fp32 compute, f16 out.
__device__ __forceinline__ void dwbn_one(
    const float* __restrict__ x, const float* __restrict__ dw,
    const float* __restrict__ gamma, const float* __restrict__ beta,
    const float* __restrict__ mean,  const float* __restrict__ var,
    f16* __restrict__ out, int OH, int OW, int stride, int idx)
{
    int c4 = idx % (C_/4);
    int sp = idx / (C_/4);
    int ox = sp % OW;
    int t2 = sp / OW;
    int oy = t2 % OH;
    int b  = t2 / OH;
    int c0 = c4*4;
    float4 acc = make_float4(0.f,0.f,0.f,0.f);
    int iy0 = oy*stride - 1;
    int ix0 = ox*stride - 1;
    #pragma unroll
    for (int ky = 0; ky < 3; ++ky) {
        int iy = iy0 + ky;
        if (iy < 0 || iy >= HH) continue;
        #pragma unroll
        for (int kx = 0; kx < 3; ++kx) {
            int ix = ix0 + kx;
            if (ix < 0 || ix >= WW) continue;
            float4 xv = *reinterpret_cast<const float4*>(
                x + ((size_t)b*NN + iy*WW + ix)*C_ + c0);
            int wi = ky*3 + kx;
            acc.x = fmaf(dw[(c0+0)*9 + wi], xv.x, acc.x);
            acc.y = fmaf(dw[(c0+1)*9 + wi], xv.y, acc.y);
            acc.z = fmaf(dw[(c0+2)*9 + wi], xv.z, acc.z);
            acc.w = fmaf(dw[(c0+3)*9 + wi], xv.w, acc.w);
        }
    }
    float i0 = gamma[c0+0]*__frsqrt_rn(var[c0+0] + 1e-5f);
    float i1 = gamma[c0+1]*__frsqrt_rn(var[c0+1] + 1e-5f);
    float i2 = gamma[c0+2]*__frsqrt_rn(var[c0+2] + 1e-5f);
    float i3 = gamma[c0+3]*__frsqrt_rn(var[c0+3] + 1e-5f);
    f16x4 r;
    r[0] = (f16)(acc.x*i0 + (beta[c0+0] - mean[c0+0]*i0));
    r[1] = (f16)(acc.y*i1 + (beta[c0+1] - mean[c0+1]*i1));
    r[2] = (f16)(acc.z*i2 + (beta[c0+2] - mean[c0+2]*i2));
    r[3] = (f16)(acc.w*i3 + (beta[c0+3] - mean[c0+3]*i3));
    *reinterpret_cast<f16x4*>(out + (size_t)idx*4) = r;
}

__global__ __launch_bounds__(256) void dwbn_both(
    const float* __restrict__ x,
    const float* __restrict__ dwq,  const float* __restrict__ gq,
    const float* __restrict__ bq_,  const float* __restrict__ mq,
    const float* __restrict__ vq,
    const float* __restrict__ dwkv, const float* __restrict__ gkv,
    const float* __restrict__ bkv,  const float* __restrict__ mkv,
    const float* __restrict__ vkv,
    f16* __restrict__ uq, f16* __restrict__ ukv)
{
    int idx = blockIdx.x*256 + threadIdx.x;
    const int totq = BB*NN*(C_/4);          // 1204224
    const int totk = BB*MM*(C_/4);          // 301056
    if (idx < totq) {
        dwbn_one(x, dwq, gq, bq_, mq, vq, uq, HH, WW, 1, idx);
    } else {
        int i2 = idx - totq;
        if (i2 < totk)
            dwbn_one(x, dwkv, gkv, bkv, mkv, vkv, ukv, 28, 28, 2, i2);
    }
}

// ---------------------------------------------------------------------------
// All projections, one launch. blocks 0..391: Q path (64 rows each).
// blocks 392..489: KV path — A-fragments loaded once, used for K and V.
// Ping-pong prefetch of B-fragments across the 12 column-tiles.
__global__ __launch_bounds__(256, 1) void proj_all(
    const f16* __restrict__ uq, const f16* __restrict__ ukv,
    const f16* __restrict__ Mq, const f16* __restrict__ Mk,
    const f16* __restrict__ Mv,
    const float* __restrict__ bq, const float* __restrict__ bk,
    const float* __restrict__ bv,
    f16* __restrict__ qb, f16* __restrict__ kb, f16* __restrict__ vt)
{
    int tid  = threadIdx.x;
    int w    = tid >> 6, l = tid & 63;
    int lrow = l & 15,  lgrp = l >> 4;
    int blk  = blockIdx.x;
    bool qpath = blk < QPB;
    const f16* U = qpath ? uq : ukv;
    int r0 = (qpath ? blk : blk - QPB)*64 + w*16;

    const f16* urow = U + (size_t)(r0 + lrow)*C_;
    f16x8 a[6];
    #pragma unroll
    for (int ch = 0; ch < 6; ++ch)
        a[ch] = *(const f16x8*)(urow + ch*32 + lgrp*8);

    f16x8 bfA[6], bfB[6];

    if (qpath) {
        // scale = (1/sqrt(48)) * log2(e)  — attn softmax runs in exp2 domain
        const float qscale = 0.14433756729740643f * 1.4426950408889634f;
        #pragma unroll
        for (int ch = 0; ch < 6; ++ch)
            bfA[ch] = *(const f16x8*)(Mq + (size_t)lrow*C_ + ch*32 + lgrp*8);
        #pragma unroll
        for (int ct = 0; ct < 12; ++ct) {
            f16x8* cur = (ct & 1) ? bfB : bfA;
            f16x8* nxt = (ct & 1) ? bfA : bfB;
            if (ct < 11) {
                const f16* mrow = Mq + (size_t)((ct+1)*16 + lrow)*C_;
                #pragma unroll
                for (int ch = 0; ch < 6; ++ch)
                    nxt[ch] = *(const f16x8*)(mrow + ch*32 + lgrp*8);
            }
            int o = ct*16 + lrow;
            f32x4 acc = {0.f,0.f,0.f,0.f};
            #pragma unroll
            for (int ch = 0; ch < 6; ++ch)
                acc = MFMA16(a[ch], cur[ch], acc);
            float bo = bq[o];
            #pragma unroll
            for (int i = 0; i < 4; ++i)
                qb[(size_t)(r0 + lgrp*4 + i)*C_ + o] = (f16)((acc[i] + bo)*qscale);
        }
    } else {
        #pragma unroll
        for (int ch = 0; ch < 6; ++ch)
            bfA[ch] = *(const f16x8*)(Mk + (size_t)lrow*C_ + ch*32 + lgrp*8);
        #pragma unroll
        for (int ct = 0; ct < 12; ++ct) {            // K projection
            f16x8* cur = (ct & 1) ? bfB : bfA;
            f16x8* nxt = (ct & 1) ? bfA : bfB;
            const f16* nrow = (ct < 11) ? Mk + (size_t)((ct+1)*16 + lrow)*C_
                                        : Mv + (size_t)lrow*C_;
            #pragma unroll
            for (int ch = 0; ch < 6; ++ch)
                nxt[ch] = *(const f16x8*)(nrow + ch*32 + lgrp*8);
            int o = ct*16 + lrow;
            f32x4 acc = {0.f,0.f,0.f,0.f};
            #pragma unroll
            for (int ch = 0; ch < 6; ++ch)
                acc = MFMA16(a[ch], cur[ch], acc);
            float bo = bk[o];
            #pragma unroll
            for (int i = 0; i < 4; ++i)
                kb[(size_t)(r0 + lgrp*4 + i)*C_ + o] = (f16)(acc[i] + bo);
        }
        // V: K-loop's last prefetch (ct=11, odd) put Mv tile 0 into bfA,
        // so the V loop uses the SAME parity as the K loop (even ct -> bfA).
        #pragma unroll
        for (int ct = 0; ct < 12; ++ct) {            // V projection (transposed)
            f16x8* cur = (ct & 1) ? bfB : bfA;
            f16x8* nxt = (ct & 1) ? bfA : bfB;
            if (ct < 11) {
                const f16* mrow = Mv + (size_t)((ct+1)*16 + lrow)*C_;
                #pragma unroll
                for (int ch = 0; ch < 6; ++ch)
                    nxt[ch] = *(const f16x8*)(mrow + ch*32 + lgrp*8);
            }
            int o = ct*16 + lrow;
            f32x4 acc = {0.f,0.f,0.f,0.f};
            #pragma unroll
            for (int ch = 0; ch < 6; ++ch)
                acc = MFMA16(a[ch], cur[ch], acc);
            float bo = bv[o];
            int rg = r0 + lgrp*4;
            int b  = rg / MM, m = rg % MM;            // 784 % 16 == 0, no straddle
            #pragma unroll
            for (int i = 0; i < 4; ++i)
                vt[((size_t)b*C_ + o)*VT_LD + m + i] = (f16)(acc[i] + bo);
        }
    }
}

// ---------------------------------------------------------------------------
// Flash attention R8: 32-key double-buffered register tiles (fits VGPR budget
// so the prefetch REALLY stays in flight), 4 waves/block sharing (b,h) K/V
// (L1 reuse), swapped-operand MFMA, lane-local softmax, zero LDS/barriers.
struct Tile {
    f16x8 ka0, ka1;   // keys m0+lrow      : d 0..31 | d 32..63
    f16x8 kb0, kb1;   // keys m0+16+lrow
    f16x8 v0, v1, v2; // Vt rows lrow, +16, +32 ; cols m0 + g*8 ..
};

__device__ __forceinline__ void load_tile(
    Tile& T, const f16* __restrict__ kbb, const f16* __restrict__ vbb,
    int m0, int lrow, int g)
{
    const f16* r0 = kbb + (size_t)(m0 + lrow)*C_;
    const f16* r1 = kbb + (size_t)(m0 + 16 + lrow)*C_;
    T.ka0 = *(const f16x8*)(r0 + g*8);
    T.ka1 = *(const f16x8*)(r0 + 32 + g*8);
    T.kb0 = *(const f16x8*)(r1 + g*8);
    T.kb1 = *(const f16x8*)(r1 + 32 + g*8);
    T.v0  = *(const f16x8*)(vbb + m0 + g*8);
    T.v1  = *(const f16x8*)(vbb + 16*VT_LD + m0 + g*8);
    T.v2  = *(const f16x8*)(vbb + 32*VT_LD + m0 + g*8);
}

__device__ __forceinline__ void qk_tile(
    const Tile& T, const f16x8& qf0, const f16x8& qf1, f32x4& s0, f32x4& s1)
{
    f32x4 z = {0.f,0.f,0.f,0.f};
    __builtin_amdgcn_s_setprio(1);
    s0 = MFMA16(T.ka0, qf0, z);  s0 = MFMA16(T.ka1, qf1, s0);
    s1 = MFMA16(T.kb0, qf0, z);  s1 = MFMA16(T.kb1, qf1, s1);
    __builtin_amdgcn_s_setprio(0);
}

__device__ __forceinline__ void finish_tile(
    f32x4& s0, f32x4& s1, const Tile& T,
    float& mrun, float& lrun, f32x4& o0, f32x4& o1, f32x4& o2,
    int la, int lb, bool hi)
{
    float tmax = fmaxf(fmaxf(fmaxf(s0[0], s0[1]), fmaxf(s0[2], s0[3])),
                       fmaxf(fmaxf(s1[0], s1[1]), fmaxf(s1[2], s1[3])));
    tmax = fmaxf(tmax, __shfl_xor(tmax, 16));
    tmax = fmaxf(tmax, __shfl_xor(tmax, 32));
    float mnew = fmaxf(mrun, tmax);
    float corr = exp2f(mrun - mnew);
    mrun = mnew;
    float psum = 0.f;
    #pragma unroll
    for (int r = 0; r < 4; ++r) {
        s0[r] = exp2f(s0[r] - mnew); psum += s0[r];
        s1[r] = exp2f(s1[r] - mnew); psum += s1[r];
    }
    psum += __shfl_xor(psum, 16);
    psum += __shfl_xor(psum, 32);
    lrun = lrun*corr + psum;

    u32 pk00 = pkrtz(s0[0], s0[1]), pk01 = pkrtz(s0[2], s0[3]);
    u32 pk10 = pkrtz(s1[0], s1[1]), pk11 = pkrtz(s1[2], s1[3]);

    #pragma unroll
    for (int r = 0; r < 4; ++r) { o0[r] *= corr; o1[r] *= corr; o2[r] *= corr; }

    u32 a0  = __shfl(pk00, la), a0h = __shfl(pk10, la);
    u32 a1  = __shfl(pk01, la), a1h = __shfl(pk11, la);
    u32 b0  = __shfl(pk00, lb), b0h = __shfl(pk10, lb);
    u32 b1  = __shfl(pk01, lb), b1h = __shfl(pk11, lb);
    u32x4 uw = { hi ? a0h : a0, hi ? a1h : a1, hi ? b0h : b0, hi ? b1h : b1 };
    f16x8 pb = __builtin_bit_cast(f16x8, uw);

    __builtin_amdgcn_s_setprio(1);
    o0 = MFMA16(T.v0, pb, o0);
    o1 = MFMA16(T.v1, pb, o1);
    o2 = MFMA16(T.v2, pb, o2);
    __builtin_amdgcn_s_setprio(0);
}

__global__ __launch_bounds__(256, 3) void attn_mfma(
    const f16* __restrict__ qb, const f16* __restrict__ kb,
    const f16* __restrict__ vt, float* __restrict__ out)
{
    int tid  = threadIdx.x;
    int w    = tid >> 6, l = tid & 63;
    int lrow = l & 15,  g = l >> 4;
    // XCD swizzle: 1568 = 8*196; 4 (b,h) groups per XCD -> KV L2-resident.
    int swz  = (blockIdx.x & 7)*196 + (blockIdx.x >> 3);
    int bh   = swz / 49, qblk = swz % 49;
    int h    = bh & 3, b = bh >> 2;
    int n0   = qblk*64 + w*16;

    const f16* qrow = qb + ((size_t)b*NN + n0 + lrow)*C_ + h*HD;
    f16x8 qf0 = *(const f16x8*)(qrow + g*8);
    f16x8 qf1 = (f16x8){0,0,0,0,0,0,0,0};
    if (g < 2) qf1 = *(const f16x8*)(qrow + 32 + g*8);

    float mrun = -1e30f, lrun = 0.f;
    f32x4 o0 = {0.f,0.f,0.f,0.f}, o1 = o0, o2 = o0;

    int  la = lrow + ((g & 1) << 5);
    int  lb = la + 16;
    bool hi = g >= 2;

    const f16* kbb = kb + (size_t)b*MM*C_ + h*HD;
    const f16* vbb = vt + ((size_t)b*C_ + h*HD + lrow)*VT_LD;

    Tile A, Bt;
    load_tile(A, kbb, vbb, 0, lrow, g);

    f32x4 s0, s1;
    for (int p = 0; p < 12; ++p) {
        int m0 = p*64;
        // tile 2p (A); prefetch 2p+1 -> B
        qk_tile(A, qf0, qf1, s0, s1);
        load_tile(Bt, kbb, vbb, m0 + 32, lrow, g);
        finish_tile(s0, s1, A, mrun, lrun, o0, o1, o2, la, lb, hi);
        // tile 2p+1 (B); prefetch 2p+2 -> A  (p=11 loads the 16-key tail + pad)
        qk_tile(Bt, qf0, qf1, s0, s1);
        load_tile(A, kbb, vbb, m0 + 64, lrow, g);
        finish_tile(s0, s1, Bt, mrun, lrun, o0, o1, o2, la, lb, hi);
    }

    // ---- tail: keys 768..783 (16 real); kt=1 half is garbage -> ignored
    {
        f32x4 z = {0.f,0.f,0.f,0.f};
        __builtin_amdgcn_s_setprio(1);
        s0 = MFMA16(A.ka0, qf0, z);
        s0 = MFMA16(A.ka1, qf1, s0);
        __builtin_amdgcn_s_setprio(0);
        float tmax = fmaxf(fmaxf(s0[0], s0[1]), fmaxf(s0[2], s0[3]));
        tmax = fmaxf(tmax, __shfl_xor(tmax, 16));
        tmax = fmaxf(tmax, __shfl_xor(tmax, 32));
        float mnew = fmaxf(mrun, tmax);
        float corr = exp2f(mrun - mnew);
        mrun = mnew;
        float psum = 0.f;
        #pragma unroll
        for (int r = 0; r < 4; ++r) { s0[r] = exp2f(s0[r] - mnew); psum += s0[r]; }
        psum += __shfl_xor(psum, 16);
        psum += __shfl_xor(psum, 32);
        lrun = lrun*corr + psum;
        u32 pk00 = pkrtz(s0[0], s0[1]), pk01 = pkrtz(s0[2], s0[3]);
        #pragma unroll
        for (int r = 0; r < 4; ++r) { o0[r] *= corr; o1[r] *= corr; o2[r] *= corr; }
        u32 a0 = __shfl(pk00, la), a1 = __shfl(pk01, la);
        u32 b0 = __shfl(pk00, lb), b1 = __shfl(pk01, lb);
        u32x4 uw = { hi ? 0u : a0, hi ? 0u : a1, hi ? 0u : b0, hi ? 0u : b1 };
        f16x8 pb = __builtin_bit_cast(f16x8, uw);
        __builtin_amdgcn_s_setprio(1);
        o0 = MFMA16(A.v0, pb, o0);   // V cols 784..799 are zero-padded
        o1 = MFMA16(A.v1, pb, o1);
        o2 = MFMA16(A.v2, pb, o2);
        __builtin_amdgcn_s_setprio(0);
    }

    float inv = 1.f / lrun;
    f32x4 r0, r1, r2;
    #pragma unroll
    for (int r = 0; r < 4; ++r) {
        r0[r] = o0[r]*inv; r1[r] = o1[r]*inv; r2[r] = o2[r]*inv;
    }
    float* obase = out + ((size_t)b*NN + n0 + lrow)*C_ + h*HD + g*4;
    *(f32x4*)(obase)      = r0;
    *(f32x4*)(obase + 16) = r1;
    *(f32x4*)(obase + 32) = r2;
}

// ---------------------------------------------------------------------------
extern "C" void kernel_launch(void* const* d_in, const int* in_sizes, int n_in,
                              void* d_out, int out_size, void* d_ws, size_t ws_size,
                              hipStream_t stream)
{
    const float* x     = (const float*)d_in[0];
    const float* dw_q  = (const float*)d_in[3];
    const float* bnqg  = (const float*)d_in[4];
    const float* bnqb  = (const float*)d_in[5];
    const float* bnqm  = (const float*)d_in[6];
    const float* bnqv  = (const float*)d_in[7];
    const float* pw_q  = (const float*)d_in[8];
    const float* dw_kv = (const float*)d_in[9];
    const float* bnkg  = (const float*)d_in[10];
    const float* bnkb  = (const float*)d_in[11];
    const float* bnkm  = (const float*)d_in[12];
    const float* bnkvv = (const float*)d_in[13];
    const float* pw_kv = (const float*)d_in[14];
    const float* Wq    = (const float*)d_in[15];
    const float* bq    = (const float*)d_in[16];
    const float* Wk    = (const float*)d_in[17];
    const float* bk    = (const float*)d_in[18];
    const float* Wv    = (const float*)d_in[19];
    const float* bv    = (const float*)d_in[20];
    float* out = (float*)d_out;

    f16* p   = (f16*)d_ws;
    f16* Mq16  = p;  p += C_*C_;
    f16* Mk16  = p;  p += C_*C_;
    f16* Mv16  = p;  p += C_*C_;
    f16* uq16  = p;  p += (size_t)BB*NN*C_;
    f16* ukv16 = p;  p += (size_t)BB*MM*C_;
    f16* qb16  = p;  p += (size_t)BB*NN*C_ + 256;    // pad: frag tail reads
    f16* kb16  = p;  p += (size_t)BB*MM*C_ + 16384;  // pad: tail-tile prefetch overread
    f16* vt16  = p;  p += (size_t)BB*C_*VT_LD;

    setup_kernel<<<704, 192, 0, stream>>>(
        Wq, Wk, Wv, pw_q, pw_kv, Mq16, Mk16, Mv16, vt16);

    dwbn_both<<<5880, 256, 0, stream>>>(
        x, dw_q, bnqg, bnqb, bnqm, bnqv,
        dw_kv, bnkg, bnkb, bnkm, bnkvv, uq16, ukv16);

    proj_all<<<QPB + KVPB, 256, 0, stream>>>(
        uq16, ukv16, Mq16, Mk16, Mv16, bq, bk, bv, qb16, kb16, vt16);

    attn_mfma<<<1568, 256, 0, stream>>>(qb16, kb16, vt16, out);
}